// Round 2
// baseline (85.328 us; speedup 1.0000x reference)
//
#include <hip/hip_runtime.h>
#include <hip/hip_fp16.h>
#include <math.h>

// HistDRDoubleConv on gfx950.
// B=8, Cin=Cmid=Cout=8, H=W=256, R=8. Pool: k=86, s=85 -> 3x3 (windows at 0,85,170).
// Pipeline (5 kernels):
//   rowsum(x) -> rs ; buildK1(rs) -> K1(fp16) ;
//   conv1(x, K1[argmax hist]) + BN/ReLU -> y1, + fused rowsum(y1) -> rs ;
//   buildK2(rs) -> K2 ; conv2(y1, K2[regmap]) + BN/ReLU -> out.

#define HWPX 65536   // 256*256
#define HDIM 256

// ---------- rowsum: per (b,c,row): 3 column-window sums, coalesced ----------
__global__ __launch_bounds__(256) void rowsum_kernel(const float* __restrict__ in,
                                                     float* __restrict__ rs) {
  int bid = blockIdx.x;          // (b*8+c)*64 + rowgroup
  int rg = bid & 63, bc = bid >> 6;
  int wave = threadIdx.x >> 6, lane = threadIdx.x & 63;
  int row = rg * 4 + wave;
  const float4 v = *(const float4*)(in + (size_t)bc * HWPX + row * HDIM + lane * 4);
  float s0 = 0.f, s1 = 0.f, s2 = 0.f;
#pragma unroll
  for (int p = 0; p < 4; p++) {
    int px = lane * 4 + p;
    float val = (&v.x)[p];
    if (px <= 85) s0 += val;
    if (px >= 85 && px <= 170) s1 += val;
    if (px >= 170) s2 += val;
  }
#pragma unroll
  for (int off = 32; off >= 1; off >>= 1) {
    s0 += __shfl_xor(s0, off);
    s1 += __shfl_xor(s1, off);
    s2 += __shfl_xor(s2, off);
  }
  if (lane == 0) {
    float* q = rs + ((size_t)bc * 256 + row) * 3;
    q[0] = s0; q[1] = s1; q[2] = s2;
  }
}

// ---------- buildK: per b: rowsums -> pool -> sigmoid -> fp16 kernels --------
__global__ __launch_bounds__(256) void buildK_kernel(const float* __restrict__ rs,
                                                     const float* __restrict__ wa,
                                                     const float* __restrict__ ba,
                                                     const float* __restrict__ wb,
                                                     const float* __restrict__ bb,
                                                     __half* __restrict__ Kg) {
  int b = blockIdx.x;
  __shared__ float pp[72][3];
  __shared__ float p[8][9];
  __shared__ float h[576];       // h[(rr*8+cc)*9 + tap]
  int t = threadIdx.x;
  if (t < 216) {
    int u = t / 3, part = t - 3 * (t / 3);
    int c = u / 9, ij = u % 9, i = ij / 3, j = ij % 3;
    int r0 = 85 * i + part * 29;
    int cnt = (part == 2) ? 28 : 29;
    const float* q = rs + ((size_t)(b * 8 + c) * 256 + r0) * 3 + j;
    float s = 0.f;
    for (int k = 0; k < cnt; k++) s += q[k * 3];
    pp[u][part] = s;
  }
  __syncthreads();
  if (t < 72) p[t / 9][t % 9] = (pp[t][0] + pp[t][1] + pp[t][2]) * (1.f / 7396.f);
  __syncthreads();
  for (int u = t; u < 576; u += 256) {
    int o = u / 9, ij = u - o * 9;          // o = rr*8+cc
    float z = ba[o];
#pragma unroll
    for (int c = 0; c < 8; c++) z += p[c][ij] * wa[o * 8 + c];
    h[o * 9 + ij] = 1.f / (1.f + expf(-z));
  }
  __syncthreads();
  for (int u = t; u < 4608; u += 256) {
    int r = u / 576, w = u - r * 576;
    int oc = w & 7, vv = w >> 3, tap = vv % 9, ci = vv / 9;
    int row = r * 64 + oc * 8 + ci;
    float val = bb[row];
#pragma unroll
    for (int cc = 0; cc < 8; cc++) val += h[(r * 8 + cc) * 9 + tap] * wb[row * 8 + cc];
    Kg[(size_t)b * 4608 + u] = __float2half(val);
  }
}

// ---------- conv + BN + ReLU (+ regmap & fused rowsum for LAYER 1) ----------
// K in LDS as fp16, region stride 584 halfs: region r's b128 reads hit bank
// quad 4r..4r+3 -> 8 random regions across a wave are conflict-free.
template <int LAYER>
__global__ __launch_bounds__(256) void conv_kernel(
    const float* __restrict__ x, const float* __restrict__ hist,
    const unsigned char* __restrict__ regin, unsigned char* __restrict__ regout,
    const __half* __restrict__ Kg,
    const float* __restrict__ g, const float* __restrict__ be,
    const float* __restrict__ m, const float* __restrict__ v,
    float* __restrict__ out, float* __restrict__ rs2) {
  __shared__ __half Ks[8 * 584];
  __shared__ float bns[8], bnsh[8];
  __shared__ float wred[4][8][3];

  int bid = blockIdx.x;
  int nb = (bid & 7) * 256 + (bid >> 3);   // XCD swizzle: one batch per XCD
  int b = nb >> 8;
  int row = nb & 255;

  // stage K (4608 halfs) as dwords
  const uint* Kw = (const uint*)(Kg + (size_t)b * 4608);
  for (int t = threadIdx.x; t < 2304; t += 256) {
    int rr = t / 288;
    *(uint*)((ushort*)Ks + rr * 584 + (t - rr * 288) * 2) = Kw[t];
  }
  if (threadIdx.x < 8) {
    float s = g[threadIdx.x] * rsqrtf(v[threadIdx.x] + 1e-5f);
    bns[threadIdx.x] = s;
    bnsh[threadIdx.x] = be[threadIdx.x] - m[threadIdx.x] * s;
  }
  __syncthreads();

  int x0 = threadIdx.x;
  int pix = (row << 8) | x0;
  int reg;
  if (LAYER == 1) {
    const float* hp = hist + (size_t)b * 8 * HWPX + pix;
    float best = hp[0];
    reg = 0;
#pragma unroll
    for (int r = 1; r < 8; r++) {
      float hv = hp[(size_t)r * HWPX];
      if (hv > best) { best = hv; reg = r; }   // strict > == JAX first-max
    }
    regout[b * HWPX + pix] = (unsigned char)reg;
  } else {
    reg = regin[b * HWPX + pix];
  }

  const __half* Kr = Ks + reg * 584;
  float acc[8] = {0.f, 0.f, 0.f, 0.f, 0.f, 0.f, 0.f, 0.f};
  const float* xb = x + (size_t)b * 8 * HWPX;
#pragma unroll
  for (int di = 0; di < 3; di++) {
    int yy = row + di - 1;
    if ((unsigned)yy >= 256u) continue;
#pragma unroll
    for (int dj = 0; dj < 3; dj++) {
      int xx = x0 + dj - 1;
      if ((unsigned)xx >= 256u) continue;
      int tap = di * 3 + dj;
      const float* xp = xb + yy * HDIM + xx;
#pragma unroll
      for (int ci = 0; ci < 8; ci++) {
        float xv = xp[(size_t)ci * HWPX];
        const uint4 kw = *(const uint4*)(Kr + ci * 72 + tap * 8);
        float2 f0 = __half22float2(*(const __half2*)&kw.x);
        float2 f1 = __half22float2(*(const __half2*)&kw.y);
        float2 f2 = __half22float2(*(const __half2*)&kw.z);
        float2 f3 = __half22float2(*(const __half2*)&kw.w);
        acc[0] += xv * f0.x; acc[1] += xv * f0.y;
        acc[2] += xv * f1.x; acc[3] += xv * f1.y;
        acc[4] += xv * f2.x; acc[5] += xv * f2.y;
        acc[6] += xv * f3.x; acc[7] += xv * f3.y;
      }
    }
  }

  float* op = out + (size_t)b * 8 * HWPX + pix;
#pragma unroll
  for (int oc = 0; oc < 8; oc++) {
    acc[oc] = fmaxf(acc[oc] * bns[oc] + bnsh[oc], 0.f);
    op[(size_t)oc * HWPX] = acc[oc];
  }

  if (LAYER == 1) {
    // fused rowsum of y1 for layer-2 pool: 3 column-window sums per (oc,row)
    int wv = threadIdx.x >> 6, ln = threadIdx.x & 63;
    bool in0 = (x0 <= 85), in1 = (x0 >= 85 && x0 <= 170), in2 = (x0 >= 170);
#pragma unroll
    for (int oc = 0; oc < 8; oc++) {
      float v0 = in0 ? acc[oc] : 0.f;
      float v1 = in1 ? acc[oc] : 0.f;
      float v2 = in2 ? acc[oc] : 0.f;
#pragma unroll
      for (int off = 32; off >= 1; off >>= 1) {
        v0 += __shfl_xor(v0, off);
        v1 += __shfl_xor(v1, off);
        v2 += __shfl_xor(v2, off);
      }
      if (ln == 0) { wred[wv][oc][0] = v0; wred[wv][oc][1] = v1; wred[wv][oc][2] = v2; }
    }
    __syncthreads();
    if (threadIdx.x < 24) {
      int oc = threadIdx.x / 3, j = threadIdx.x - 3 * oc;
      float s = wred[0][oc][j] + wred[1][oc][j] + wred[2][oc][j] + wred[3][oc][j];
      rs2[((size_t)(b * 8 + oc) * 256 + row) * 3 + j] = s;
    }
  }
}

extern "C" void kernel_launch(void* const* d_in, const int* in_sizes, int n_in,
                              void* d_out, int out_size, void* d_ws, size_t ws_size,
                              hipStream_t stream) {
  const float* x    = (const float*)d_in[0];
  const float* hist = (const float*)d_in[1];
  const float* w1a  = (const float*)d_in[2];
  const float* b1a  = (const float*)d_in[3];
  const float* w1b  = (const float*)d_in[4];
  const float* b1b  = (const float*)d_in[5];
  const float* g1   = (const float*)d_in[6];
  const float* be1  = (const float*)d_in[7];
  const float* m1   = (const float*)d_in[8];
  const float* v1   = (const float*)d_in[9];
  const float* w2a  = (const float*)d_in[10];
  const float* b2a  = (const float*)d_in[11];
  const float* w2b  = (const float*)d_in[12];
  const float* b2b  = (const float*)d_in[13];
  const float* g2   = (const float*)d_in[14];
  const float* be2  = (const float*)d_in[15];
  const float* m2   = (const float*)d_in[16];
  const float* v2   = (const float*)d_in[17];
  float* outp = (float*)d_out;

  char* ws = (char*)d_ws;
  unsigned char* regmap = (unsigned char*)ws;            // 524288 B
  float* y1  = (float*)(ws + 524288);                    // 16 MiB
  float* rsA = (float*)(ws + 17301504);                  // 196608 B (rs1 then rs2)
  __half* KgA = (__half*)(ws + 17498112);                // 73728 B (K1 then K2)

  rowsum_kernel<<<4096, 256, 0, stream>>>(x, rsA);
  buildK_kernel<<<8, 256, 0, stream>>>(rsA, w1a, b1a, w1b, b1b, KgA);
  conv_kernel<1><<<2048, 256, 0, stream>>>(x, hist, nullptr, regmap, KgA,
                                           g1, be1, m1, v1, y1, rsA);
  buildK_kernel<<<8, 256, 0, stream>>>(rsA, w2a, b2a, w2b, b2b, KgA);
  conv_kernel<2><<<2048, 256, 0, stream>>>(y1, nullptr, regmap, nullptr, KgA,
                                           g2, be2, m2, v2, outp, nullptr);
}

// Round 4
// 74.279 us; speedup vs baseline: 1.1487x; 1.1487x over previous
//
#include <hip/hip_runtime.h>
#include <math.h>

// HistDRDoubleConv on gfx950.
// B=8, Cin=Cmid=Cout=8, H=W=256, R=8. Pool: k=86, s=85 -> 3x3 (windows at 0,85,170).
// Pipeline (6 kernels):
//   rowsum(x) -> rs ; buildK1 -> K1(fp16, dot2 layout) ;
//   conv1(x, K1[argmax hist]) + BN/ReLU -> y1 ;
//   rowsum(y1) -> rs ; buildK2 -> K2 ; conv2(y1, K2[regmap]) + BN/ReLU -> out.
// Conv inner loop: v_dot2_f32_f16 over ci-pairs, K staged in LDS with region
// stride 1168 B so different-region lanes hit disjoint bank quads.

#define HWPX 65536   // 256*256
#define HDIM 256

typedef __fp16 h2 __attribute__((ext_vector_type(2)));

#if defined(__has_builtin) && __has_builtin(__builtin_amdgcn_fdot2)
__device__ __forceinline__ float fdot2(h2 a, h2 b, float c) {
  return __builtin_amdgcn_fdot2(a, b, c, false);
}
#else
__device__ __forceinline__ float fdot2(h2 a, h2 b, float c) {
  return c + (float)a[0] * (float)b[0] + (float)a[1] * (float)b[1];
}
#endif

union U4H {
  uint4 u;
  h2 h[4];
};

// ---------- rowsum: per (b,c,row): 3 column-window sums, coalesced ----------
__global__ __launch_bounds__(256) void rowsum_kernel(const float* __restrict__ in,
                                                     float* __restrict__ rs) {
  int bid = blockIdx.x;          // (b*8+c)*64 + rowgroup
  int rg = bid & 63, bc = bid >> 6;
  int wave = threadIdx.x >> 6, lane = threadIdx.x & 63;
  int row = rg * 4 + wave;
  const float4 v = *(const float4*)(in + (size_t)bc * HWPX + row * HDIM + lane * 4);
  float s0 = 0.f, s1 = 0.f, s2 = 0.f;
#pragma unroll
  for (int p = 0; p < 4; p++) {
    int px = lane * 4 + p;
    float val = (&v.x)[p];
    if (px <= 85) s0 += val;
    if (px >= 85 && px <= 170) s1 += val;
    if (px >= 170) s2 += val;
  }
#pragma unroll
  for (int off = 32; off >= 1; off >>= 1) {
    s0 += __shfl_xor(s0, off);
    s1 += __shfl_xor(s1, off);
    s2 += __shfl_xor(s2, off);
  }
  if (lane == 0) {
    float* q = rs + ((size_t)bc * 256 + row) * 3;
    q[0] = s0; q[1] = s1; q[2] = s2;
  }
}

// ---------- buildK: per b: rowsums -> pool -> sigmoid -> fp16 kernels --------
// Output layout (halfs): Kg[b][reg][tap][oc][ci]  (ci fastest, pairs for dot2)
__global__ __launch_bounds__(256) void buildK_kernel(const float* __restrict__ rs,
                                                     const float* __restrict__ wa,
                                                     const float* __restrict__ ba,
                                                     const float* __restrict__ wb,
                                                     const float* __restrict__ bb,
                                                     __fp16* __restrict__ Kg) {
  int b = blockIdx.x;
  __shared__ float pp[72][3];
  __shared__ float p[8][9];
  __shared__ float h[576];       // h[(rr*8+cc)*9 + tap]
  int t = threadIdx.x;
  if (t < 216) {
    int u = t / 3, part = t - 3 * (t / 3);
    int c = u / 9, ij = u % 9, i = ij / 3, j = ij % 3;
    int r0 = 85 * i + part * 29;
    int cnt = (part == 2) ? 28 : 29;
    const float* q = rs + ((size_t)(b * 8 + c) * 256 + r0) * 3 + j;
    float s = 0.f;
    for (int k = 0; k < cnt; k++) s += q[k * 3];
    pp[u][part] = s;
  }
  __syncthreads();
  if (t < 72) p[t / 9][t % 9] = (pp[t][0] + pp[t][1] + pp[t][2]) * (1.f / 7396.f);
  __syncthreads();
  for (int u = t; u < 576; u += 256) {
    int o = u / 9, ij = u - o * 9;          // o = rr*8+cc
    float z = ba[o];
#pragma unroll
    for (int c = 0; c < 8; c++) z += p[c][ij] * wa[o * 8 + c];
    h[o * 9 + ij] = 1.f / (1.f + expf(-z));
  }
  __syncthreads();
  for (int u = t; u < 4608; u += 256) {
    int reg = u / 576, w = u - reg * 576;
    int tap = w >> 6, z = w & 63, oc = z >> 3, ci = z & 7;
    int row = reg * 64 + oc * 8 + ci;
    float val = bb[row];
#pragma unroll
    for (int cc = 0; cc < 8; cc++) val += h[(reg * 8 + cc) * 9 + tap] * wb[row * 8 + cc];
    Kg[(size_t)b * 4608 + u] = (__fp16)val;
  }
}

// ---------- conv + BN + ReLU (+ regmap for LAYER 1) -------------------------
// K in LDS: region stride 292 dwords (1168 B). Within region: tap*32dw + oc*4dw.
// Lane bank group = (4*reg + 4*oc + j) % 32 -> 8 regions x 4 banks, conflict-free.
template <int LAYER>
__global__ __launch_bounds__(256) void conv_kernel(
    const float* __restrict__ x, const float* __restrict__ hist,
    const unsigned char* __restrict__ regin, unsigned char* __restrict__ regout,
    const __fp16* __restrict__ Kg,
    const float* __restrict__ g, const float* __restrict__ be,
    const float* __restrict__ m, const float* __restrict__ v,
    float* __restrict__ out) {
  __shared__ uint KsU[8 * 292];        // 9344 B
  __shared__ float bns[8], bnsh[8];

  int bid = blockIdx.x;
  int nb = (bid & 7) * 256 + (bid >> 3);   // XCD swizzle: one batch per XCD
  int b = nb >> 8;
  int row = nb & 255;

  const uint* Kw = (const uint*)(Kg + (size_t)b * 4608);
  for (int t = threadIdx.x; t < 2304; t += 256) {
    int rr = t / 288;
    KsU[rr * 292 + (t - rr * 288)] = Kw[t];
  }
  if (threadIdx.x < 8) {
    float s = g[threadIdx.x] * rsqrtf(v[threadIdx.x] + 1e-5f);
    bns[threadIdx.x] = s;
    bnsh[threadIdx.x] = be[threadIdx.x] - m[threadIdx.x] * s;
  }
  __syncthreads();

  int x0 = threadIdx.x;
  int pix = (row << 8) | x0;
  int reg;
  if (LAYER == 1) {
    const float* hp = hist + (size_t)b * 8 * HWPX + pix;
    float best = hp[0];
    reg = 0;
#pragma unroll
    for (int r = 1; r < 8; r++) {
      float hv = hp[(size_t)r * HWPX];
      if (hv > best) { best = hv; reg = r; }   // strict > == JAX first-max
    }
    regout[b * HWPX + pix] = (unsigned char)reg;
  } else {
    reg = regin[b * HWPX + pix];
  }

  const char* Kr = (const char*)KsU + reg * 1168;
  float acc[8] = {0.f, 0.f, 0.f, 0.f, 0.f, 0.f, 0.f, 0.f};
  const float* xb = x + (size_t)b * 8 * HWPX;
#pragma unroll
  for (int di = 0; di < 3; di++) {
    int yy = row + di - 1;
    if ((unsigned)yy >= 256u) continue;
#pragma unroll
    for (int dj = 0; dj < 3; dj++) {
      int xx = x0 + dj - 1;
      if ((unsigned)xx >= 256u) continue;
      int tap = di * 3 + dj;
      const float* xp = xb + yy * HDIM + xx;
      float xv0 = xp[0];
      float xv1 = xp[HWPX];
      float xv2 = xp[2 * HWPX];
      float xv3 = xp[3 * HWPX];
      float xv4 = xp[4 * HWPX];
      float xv5 = xp[5 * HWPX];
      float xv6 = xp[6 * HWPX];
      float xv7 = xp[7 * HWPX];
      h2 p01 = __builtin_amdgcn_cvt_pkrtz(xv0, xv1);
      h2 p23 = __builtin_amdgcn_cvt_pkrtz(xv2, xv3);
      h2 p45 = __builtin_amdgcn_cvt_pkrtz(xv4, xv5);
      h2 p67 = __builtin_amdgcn_cvt_pkrtz(xv6, xv7);
      const char* kt = Kr + tap * 128;
#pragma unroll
      for (int oc = 0; oc < 8; oc++) {
        U4H kw;
        kw.u = *(const uint4*)(kt + oc * 16);
        float a = acc[oc];
        a = fdot2(p01, kw.h[0], a);
        a = fdot2(p23, kw.h[1], a);
        a = fdot2(p45, kw.h[2], a);
        a = fdot2(p67, kw.h[3], a);
        acc[oc] = a;
      }
    }
  }

  float* op = out + (size_t)b * 8 * HWPX + pix;
#pragma unroll
  for (int oc = 0; oc < 8; oc++) {
    op[(size_t)oc * HWPX] = fmaxf(acc[oc] * bns[oc] + bnsh[oc], 0.f);
  }
}

extern "C" void kernel_launch(void* const* d_in, const int* in_sizes, int n_in,
                              void* d_out, int out_size, void* d_ws, size_t ws_size,
                              hipStream_t stream) {
  const float* x    = (const float*)d_in[0];
  const float* hist = (const float*)d_in[1];
  const float* w1a  = (const float*)d_in[2];
  const float* b1a  = (const float*)d_in[3];
  const float* w1b  = (const float*)d_in[4];
  const float* b1b  = (const float*)d_in[5];
  const float* g1   = (const float*)d_in[6];
  const float* be1  = (const float*)d_in[7];
  const float* m1   = (const float*)d_in[8];
  const float* v1   = (const float*)d_in[9];
  const float* w2a  = (const float*)d_in[10];
  const float* b2a  = (const float*)d_in[11];
  const float* w2b  = (const float*)d_in[12];
  const float* b2b  = (const float*)d_in[13];
  const float* g2   = (const float*)d_in[14];
  const float* be2  = (const float*)d_in[15];
  const float* m2   = (const float*)d_in[16];
  const float* v2   = (const float*)d_in[17];
  float* outp = (float*)d_out;

  char* ws = (char*)d_ws;
  unsigned char* regmap = (unsigned char*)ws;            // 524288 B
  float* y1  = (float*)(ws + 524288);                    // 16 MiB
  float* rsA = (float*)(ws + 17301504);                  // 196608 B
  __fp16* Kg1 = (__fp16*)(ws + 17498112);                // 9216 B
  __fp16* Kg2 = (__fp16*)(ws + 17507328);                // 9216 B

  rowsum_kernel<<<4096, 256, 0, stream>>>(x, rsA);
  buildK_kernel<<<8, 256, 0, stream>>>(rsA, w1a, b1a, w1b, b1b, Kg1);
  conv_kernel<1><<<2048, 256, 0, stream>>>(x, hist, nullptr, regmap, Kg1,
                                           g1, be1, m1, v1, y1);
  rowsum_kernel<<<4096, 256, 0, stream>>>(y1, rsA);
  buildK_kernel<<<8, 256, 0, stream>>>(rsA, w2a, b2a, w2b, b2b, Kg2);
  conv_kernel<2><<<2048, 256, 0, stream>>>(y1, nullptr, regmap, nullptr, Kg2,
                                           g2, be2, m2, v2, outp);
}